// Round 1
// baseline (3585.418 us; speedup 1.0000x reference)
//
#include <hip/hip_runtime.h>
#include <math.h>

#define L_LAYERS 8
#define NRBF 256
#define FDIM 16
#define OUTD 3

// Workspace layout:
//   PK[n][j][k][2] = { A, -2*A*C }   where A = exp(betas[j,n,k]), C = centers[j,n,k]
//       size = NRBF * L * F * 2 = 65536 floats (256 KB)
//   AUX[n][32]: [0..7] = t3p[j] = sum_k A*C*C ; [8+o*8+j] = W[o][j*256+n]
//       size = NRBF * 32 = 8192 floats (32 KB)

__global__ __launch_bounds__(256) void prep_kernel(
    const float* __restrict__ centers, const float* __restrict__ betas,
    const float* __restrict__ W, float* __restrict__ PK, float* __restrict__ AUX)
{
    int t = blockIdx.x * blockDim.x + threadIdx.x;   // need NRBF*L = 2048 threads
    if (t >= NRBF * L_LAYERS) return;
    int n = t >> 3;
    int j = t & 7;
    const float* bp = betas   + ((size_t)j * NRBF + n) * FDIM;
    const float* cp = centers + ((size_t)j * NRBF + n) * FDIM;
    float* pk = PK + ((size_t)n * L_LAYERS + j) * FDIM * 2;
    float t3 = 0.f;
#pragma unroll
    for (int k = 0; k < FDIM; ++k) {
        float a = __expf(bp[k]);
        float c = cp[k];
        pk[2 * k]     = a;
        pk[2 * k + 1] = -2.0f * a * c;
        t3 = fmaf(a * c, c, t3);
    }
    AUX[n * 32 + j] = t3;
#pragma unroll
    for (int o = 0; o < OUTD; ++o)
        AUX[n * 32 + 8 + o * 8 + j] = W[(size_t)o * (L_LAYERS * NRBF) + j * NRBF + n];
}

// 4 threads per sample: thread q in [0,4) handles n in [q*64, q*64+64).
// x[128] lives in VGPRs. Two running-sum accumulators (even/odd k) for ILP.
__global__ __launch_bounds__(256, 2) void rbf_main(
    const float* __restrict__ feats, const float* __restrict__ PK,
    const float* __restrict__ AUX, const float* __restrict__ bias,
    float* __restrict__ out, int B)
{
    int t = blockIdx.x * 256 + threadIdx.x;
    int b = t >> 2;
    int q = t & 3;
    bool valid = (b < B);
    int bb = valid ? b : (B - 1);

    float x[128];
    const float4* xp = (const float4*)(feats + (size_t)bb * (L_LAYERS * FDIM));
#pragma unroll
    for (int i = 0; i < 32; ++i) {
        float4 v = xp[i];
        x[4 * i + 0] = v.x; x[4 * i + 1] = v.y;
        x[4 * i + 2] = v.z; x[4 * i + 3] = v.w;
    }

    float acc0 = 0.f, acc1 = 0.f, acc2 = 0.f;
    int n0 = q * (NRBF / 4);

    for (int ni = 0; ni < NRBF / 4; ++ni) {
        int n = n0 + ni;
        const float4* pk = (const float4*)(PK + (size_t)n * (L_LAYERS * FDIM * 2));
        const float4* auxv = (const float4*)(AUX + (size_t)n * 32);

        // preload aux block (8 float4 = 32 floats) so the compiler can hoist
        float auxr[32];
#pragma unroll
        for (int i = 0; i < 8; ++i) {
            float4 v = auxv[i];
            auxr[4 * i + 0] = v.x; auxr[4 * i + 1] = v.y;
            auxr[4 * i + 2] = v.z; auxr[4 * i + 3] = v.w;
        }

        float Se = 0.f, So = 0.f;
#pragma unroll
        for (int j = 0; j < L_LAYERS; ++j) {
#pragma unroll
            for (int k = 0; k < FDIM; k += 2) {
                float4 v = pk[j * 8 + (k >> 1)];   // {A_k, -2AC_k, A_k+1, -2AC_k+1}
                float xe = x[j * FDIM + k];
                float xo = x[j * FDIM + k + 1];
                Se = fmaf(xe, fmaf(v.x, xe, v.y), Se);
                So = fmaf(xo, fmaf(v.z, xo, v.w), So);
            }
            Se += auxr[j];                          // + sum_k A*C*C for layer j
            float r = __expf(-0.5f * (Se + So));    // rbf for prefix-length j+1
            acc0 = fmaf(auxr[8 + j],  r, acc0);
            acc1 = fmaf(auxr[16 + j], r, acc1);
            acc2 = fmaf(auxr[24 + j], r, acc2);
        }
    }

    // reduce over the 4 co-sample lanes (lane groups 4b..4b+3, 4-aligned in wave)
    acc0 += __shfl_xor(acc0, 1); acc0 += __shfl_xor(acc0, 2);
    acc1 += __shfl_xor(acc1, 1); acc1 += __shfl_xor(acc1, 2);
    acc2 += __shfl_xor(acc2, 1); acc2 += __shfl_xor(acc2, 2);

    if (valid && q < OUTD) {
        float r = (q == 0) ? acc0 : (q == 1) ? acc1 : acc2;
        out[(size_t)b * OUTD + q] = r + bias[q];
    }
}

extern "C" void kernel_launch(void* const* d_in, const int* in_sizes, int n_in,
                              void* d_out, int out_size, void* d_ws, size_t ws_size,
                              hipStream_t stream) {
    // inputs: 0=x (UNUSED by reference), 1=feats, 2=centers, 3=betas, 4=W, 5=b
    const float* feats   = (const float*)d_in[1];
    const float* centers = (const float*)d_in[2];
    const float* betas   = (const float*)d_in[3];
    const float* W       = (const float*)d_in[4];
    const float* bias    = (const float*)d_in[5];
    float* out = (float*)d_out;
    int B = in_sizes[1] / (L_LAYERS * FDIM);

    float* PK  = (float*)d_ws;                          // 65536 floats
    float* AUX = PK + (size_t)NRBF * L_LAYERS * FDIM * 2; // 8192 floats

    prep_kernel<<<(NRBF * L_LAYERS + 255) / 256, 256, 0, stream>>>(centers, betas, W, PK, AUX);

    int threads = B * 4;
    int blocks  = (threads + 255) / 256;
    rbf_main<<<blocks, 256, 0, stream>>>(feats, PK, AUX, bias, out, B);
}

// Round 2
// 171.423 us; speedup vs baseline: 20.9156x; 20.9156x over previous
//
#include <hip/hip_runtime.h>
#include <math.h>

#define LN 8      // layers
#define NRBF 256
#define FD 16
#define OUTD 3

typedef __attribute__((ext_vector_type(8))) short short8;   // 8 x bf16
typedef __attribute__((ext_vector_type(4))) float floatx4;

__device__ __forceinline__ short f2bf(float f) {
    unsigned u = __builtin_bit_cast(unsigned, f);
    u += 0x7fffu + ((u >> 16) & 1u);          // RNE
    return (short)(u >> 16);
}

// Workspace:
//   PKB: short8[8][16][64]   B-fragments, lane-ordered. 8192*16B = 128 KB
//        entry (j, nt, lane): n = nt*16+(lane&15), k = (lane>>4)*8+e,
//        m'=k>>1, p=k&1 -> p? -2*A*C : A   (A=exp(beta[j,n,m']))
//   EPI: float4[8][16][16]   {t3n, w0, w1, w2} at (j, nt, l), n=nt*16+l
//        t3n = -0.5*log2(e) * prefix_{j'<=j} sum_m A*C*C.  2048*16B = 32 KB

__global__ __launch_bounds__(256) void prep(
    const float* __restrict__ centers, const float* __restrict__ betas,
    const float* __restrict__ W, short* __restrict__ PKB, float* __restrict__ EPI)
{
    int t = blockIdx.x * 256 + threadIdx.x;
    if (t < 8192) {
        int lane = t & 63;
        int nt   = (t >> 6) & 15;
        int j    = t >> 10;
        int n    = nt * 16 + (lane & 15);
        int kq   = lane >> 4;
        short8 v;
#pragma unroll
        for (int e = 0; e < 8; ++e) {
            int k = kq * 8 + e;
            int m = k >> 1;
            int p = k & 1;
            size_t idx = ((size_t)(j * NRBF + n)) * FD + m;
            float a = __expf(betas[idx]);
            float c = centers[idx];
            v[e] = f2bf(p ? (-2.0f * a * c) : a);
        }
        *((short8*)(PKB + (size_t)t * 8)) = v;
    }
    if (t < 2048) {
        int j = t >> 8;
        int n = t & 255;
        float t3 = 0.f;
        for (int jj = 0; jj <= j; ++jj)
#pragma unroll
            for (int m = 0; m < FD; ++m) {
                size_t idx = ((size_t)(jj * NRBF + n)) * FD + m;
                float a = __expf(betas[idx]);
                float c = centers[idx];
                t3 = fmaf(a * c, c, t3);
            }
        int nt = n >> 4, l = n & 15;
        float* e = EPI + ((size_t)((j * 16 + nt) * 16 + l)) * 4;
        e[0] = -0.72134752f * t3;     // -0.5*log2(e) * t3_prefix
        e[1] = W[0 * (LN * NRBF) + j * NRBF + n];
        e[2] = W[1 * (LN * NRBF) + j * NRBF + n];
        e[3] = W[2 * (LN * NRBF) + j * NRBF + n];
    }
}

// One wave = 16 samples. Loop 16 n-tiles x 8 layers of 16x16x32 bf16 MFMA.
// Running accumulator across j gives the prefix sum for free.
__global__ __launch_bounds__(256, 2) void rbf_mfma(
    const float* __restrict__ feats, const short* __restrict__ PKB,
    const float* __restrict__ EPI, const float* __restrict__ bias,
    float* __restrict__ out, int B)
{
    int lane = threadIdx.x & 63;
    int wid  = threadIdx.x >> 6;
    int ntile_total = (B + 15) >> 4;
    int tile = blockIdx.x * 4 + wid;
    if (tile >= ntile_total) return;
    int b0 = tile * 16;
    int m  = lane & 15;      // sample-in-tile (A,D rows) == n-in-tile (B,D cols)
    int kq = lane >> 4;

    // Build A-fragments: lane holds sample b0+m, k-range kq*8..kq*8+7 of each layer.
    // frag = {x0^2, x0, x1^2, x1, x2^2, x2, x3^2, x3}, x_i = feats[row, j*16+kq*4+i]
    int brow = b0 + m; if (brow >= B) brow = B - 1;
    const float* xrow = feats + (size_t)brow * (LN * FD) + kq * 4;
    short8 afrag[LN];
#pragma unroll
    for (int j = 0; j < LN; ++j) {
        float4 x = *((const float4*)(xrow + j * FD));
        short8 f;
        f[0] = f2bf(x.x * x.x); f[1] = f2bf(x.x);
        f[2] = f2bf(x.y * x.y); f[3] = f2bf(x.y);
        f[4] = f2bf(x.z * x.z); f[5] = f2bf(x.z);
        f[6] = f2bf(x.w * x.w); f[7] = f2bf(x.w);
        afrag[j] = f;
    }

    const short8* pb = (const short8*)PKB;
    const float4* ep = (const float4*)EPI;
    const float KC = -0.72134752f;      // -0.5 * log2(e)

    float oacc[12];
#pragma unroll
    for (int i = 0; i < 12; ++i) oacc[i] = 0.f;

#pragma unroll 1
    for (int nt = 0; nt < 16; ++nt) {
        floatx4 acc = {0.f, 0.f, 0.f, 0.f};
#pragma unroll
        for (int j = 0; j < LN; ++j) {
            short8 bfrag = pb[(size_t)(j * 16 + nt) * 64 + lane];
            acc = __builtin_amdgcn_mfma_f32_16x16x32_bf16(afrag[j], bfrag, acc, 0, 0, 0);
            float4 e = ep[(size_t)(j * 16 + nt) * 16 + m];
#pragma unroll
            for (int r = 0; r < 4; ++r) {
                // acc[r] = prefix(term1+term2) for sample row (kq*4+r), rbf col n
                float rv = __builtin_amdgcn_exp2f(fmaf(acc[r], KC, e.x));
                oacc[r * 3 + 0] = fmaf(rv, e.y, oacc[r * 3 + 0]);
                oacc[r * 3 + 1] = fmaf(rv, e.z, oacc[r * 3 + 1]);
                oacc[r * 3 + 2] = fmaf(rv, e.w, oacc[r * 3 + 2]);
            }
        }
    }

    // Reduce over the 16 n-lanes within each kq group (xor masks 1,2,4,8 stay in-group)
#pragma unroll
    for (int i = 0; i < 12; ++i) {
        oacc[i] += __shfl_xor(oacc[i], 1);
        oacc[i] += __shfl_xor(oacc[i], 2);
        oacc[i] += __shfl_xor(oacc[i], 4);
        oacc[i] += __shfl_xor(oacc[i], 8);
    }

    if (m < OUTD) {
        float bv = bias[m];
#pragma unroll
        for (int r = 0; r < 4; ++r) {
            int row = b0 + kq * 4 + r;
            float v = (m == 0) ? oacc[r * 3 + 0] : (m == 1) ? oacc[r * 3 + 1] : oacc[r * 3 + 2];
            if (row < B) out[(size_t)row * OUTD + m] = v + bv;
        }
    }
}

extern "C" void kernel_launch(void* const* d_in, const int* in_sizes, int n_in,
                              void* d_out, int out_size, void* d_ws, size_t ws_size,
                              hipStream_t stream) {
    // inputs: 0=x (UNUSED by reference), 1=feats, 2=centers, 3=betas, 4=W, 5=b
    const float* feats   = (const float*)d_in[1];
    const float* centers = (const float*)d_in[2];
    const float* betas   = (const float*)d_in[3];
    const float* W       = (const float*)d_in[4];
    const float* bias    = (const float*)d_in[5];
    float* out = (float*)d_out;
    int B = in_sizes[1] / (LN * FD);

    short* PKB = (short*)d_ws;                       // 65536 shorts = 128 KB
    float* EPI = (float*)((char*)d_ws + 65536 * 2);  // 8192 floats = 32 KB

    prep<<<32, 256, 0, stream>>>(centers, betas, W, PKB, EPI);

    int tiles  = (B + 15) / 16;
    int blocks = (tiles + 3) / 4;
    rbf_mfma<<<blocks, 256, 0, stream>>>(feats, PKB, EPI, bias, out, B);
}